// Round 9
// baseline (672.645 us; speedup 1.0000x reference)
//
#include <hip/hip_runtime.h>

// Encoder_8718783611479: stateless per-step LSTMCell => one GEMM + elementwise.
//   gates = xt @ W_ih^T (+ b_ih + b_hh), only i,f?,g,o: f*c_prev = 0 -> i,g,o
//   out = sigmoid(sigmoid(o_g)*tanh(sigmoid(i_g)*tanh(g_g)))
// xt[b,t,k] = x[b*43200 + k*240 + t]  (K=180 strided, t contiguous)
//
// v10: single-wave blocks, zero barriers. Ledger: WRITE compact (ideal
// 172.8MB), FETCH near-ideal, W remat from L2 pack cheap, allocator refuses
// >~84 VGPR budgets; the one unfixed symptom is HBM duty 25-37% — all prior
// structures serialize stage->barrier->compute in few barrier-coupled blocks.
// Inversion: block = 1 wave owning 16t x 90h (acc[6][3]=72 VGPR), grid
// (15,2048) = 30720 wave-blocks, ~16-24 resident/CU, each independently
// staging/computing -> loads always in flight, no barrier anywhere (LDS is
// wave-synchronous). One wave owns every out line it touches -> compactness
// structural. Bias folded into GEMM via A[:,180]=1.0 and W-pack k=180 row =
// b_ih+b_hh (f32-accumulated by MFMA); epilogue has zero bias ops.
// Pre-registered risk: W L2 stream = 30720 x 110KB = 3.4GB; if time lands
// ~100-120us with HBM<50% + TCC_HIT huge -> L2-bound -> next: 2 t-tiles/wave.

#define B_SZ 2048
#define T_SZ 240
#define K_SZ 180
#define H_SZ 90
#define KP   192   // K padded to 6*32
#define TT   16    // t rows per wave-block
#define NMT  15    // t-tiles per batch

typedef __bf16 bf16x8 __attribute__((ext_vector_type(8)));
typedef __bf16 bf16x4 __attribute__((ext_vector_type(4)));
typedef float  f32x4  __attribute__((ext_vector_type(4)));

__device__ __forceinline__ float sigmoidf_(float x) {
    return __builtin_amdgcn_rcpf(1.0f + __expf(-x));
}
__device__ __forceinline__ float tanhf_(float x) {
    return 1.0f - 2.0f * __builtin_amdgcn_rcpf(__expf(2.0f * x) + 1.0f);
}

// 16-row swizzle (v9-proven): granule = 4 bf16 = 8B, key(t) = (2t)&14, even ->
// preserves granule-pair adjacency so fragment reads are single ds_read_b128.
// Write side (64 lanes b64): each bank hit 4x = floor. Read side (b128): 8
// lanes per 4-bank group = floor.
__device__ __forceinline__ int sg16(int g, int t) {
    return (g & ~15) | ((g ^ ((2 * t) & 14)) & 15);
}

// ---------------- prepack: W fragments (bias folded at k=180) ----------------
__global__ __launch_bounds__(384) void prepack_kernel(
    const float* __restrict__ W_ih,
    const float* __restrict__ b_ih,
    const float* __restrict__ b_hh,
    void* __restrict__ ws)
{
    __bf16* wp = (__bf16*)ws;
    const int gb[3] = {0, 180, 270};   // i, g, o row bases in W_ih (4H=360 rows)

    const int bid = blockIdx.x;        // 18 = 3 gates x 6 ks
    const int tid = threadIdx.x;
    const int g  = bid / 6;
    const int ks = bid % 6;
    const int w  = tid >> 6;
    const int l  = tid & 63;
    const int q  = l >> 4;
    const int n  = l & 15;
    const int h  = w * 16 + n;
    bf16x8 f;
    #pragma unroll
    for (int j = 0; j < 8; ++j) {
        int k = ks * 32 + q * 8 + j;
        float v = 0.0f;
        if (h < H_SZ) {
            if (k < K_SZ)       v = W_ih[(size_t)(gb[g] + h) * K_SZ + k];
            else if (k == K_SZ) v = b_ih[gb[g] + h] + b_hh[gb[g] + h];  // bias row
        }
        f[j] = (__bf16)v;
    }
    // fragment order: [g][ks][htile][lane] x 16B -> coalesced 16B/lane loads
    *(bf16x8*)(wp + (size_t)(((g * 6 + ks) * 6 + w) * 64 + l) * 8) = f;
}

// ---------------- main kernel: one wave per block ----------------
__global__ __launch_bounds__(64, 4) void lstm_fused_kernel(
    const float* __restrict__ x,
    const void*  __restrict__ ws,
    float* __restrict__ out)
{
    __shared__ __align__(16) __bf16 aBuf[TT * KP];   // 6 KB, swizzled [t][k]

    const int lane = threadIdx.x;   // block == 1 wave
    const int q    = lane >> 4;     // quad 0..3
    const int n    = lane & 15;
    const int mt   = blockIdx.x;    // t-tile 0..14
    const int b    = blockIdx.y;    // batch

    const float* xb = x + (size_t)b * (K_SZ * T_SZ) + mt * TT;

    // staging units: (k4 0..44, t4 0..3) -> 180 units; lanes take u, u+64, u+128
    const int k4a = lane >> 2,        t4a = lane & 3;
    const int k4b = (lane + 64) >> 2, t4b = t4a;      // (lane+64)&3 == lane&3
    const int k4c = (lane + 128) >> 2, t4c = t4a;
    const bool cv = (lane < 52);      // unit lane+128 < 180

    // ---- issue all 12 staging loads (max MLP), then pad-fill in the shadow ----
    f32x4 r0[4], r1[4], r2[4];
    {
        const float* sa = xb + (k4a * 4) * T_SZ + t4a * 4;
        const float* sb = xb + (k4b * 4) * T_SZ + t4b * 4;
        const float* sc = xb + (k4c * 4) * T_SZ + t4c * 4;
        #pragma unroll
        for (int j = 0; j < 4; ++j) r0[j] = *(const f32x4*)(sa + j * T_SZ);
        #pragma unroll
        for (int j = 0; j < 4; ++j) r1[j] = *(const f32x4*)(sb + j * T_SZ);
        if (cv) {
            #pragma unroll
            for (int j = 0; j < 4; ++j) r2[j] = *(const f32x4*)(sc + j * T_SZ);
        }
    }

    // k-padding granules 45..47: granule 45 = k 180..183 -> (1.0,0,0,0) feeds
    // the bias row of W; 46/47 zero. 16 t x 3 granules = 48 b64 writes.
    if (lane < 48) {
        int t  = lane / 3;
        int gz = 45 + (lane - (lane / 3) * 3);
        unsigned long long v = (gz == 45) ? 0x3F80ull : 0ull;  // bf16 1.0 at k=180
        *(unsigned long long*)(&aBuf[t * KP + sg16(gz, t) * 4]) = v;
    }

    // ---- register 4x4 transpose -> packed b64 swizzled LDS writes ----
#define WRITEU(R, K4, T4)                                               \
    {                                                                   \
        _Pragma("unroll")                                               \
        for (int j = 0; j < 4; ++j) {                                   \
            int t = (T4) * 4 + j;                                       \
            bf16x4 w;                                                   \
            w[0] = (__bf16)R[0][j]; w[1] = (__bf16)R[1][j];             \
            w[2] = (__bf16)R[2][j]; w[3] = (__bf16)R[3][j];             \
            *(bf16x4*)(&aBuf[t * KP + sg16((K4), t) * 4]) = w;          \
        }                                                               \
    }
    WRITEU(r0, k4a, t4a);
    WRITEU(r1, k4b, t4b);
    if (cv) WRITEU(r2, k4c, t4c);
#undef WRITEU
    // no barrier: single wave; compiler inserts the lgkmcnt before ds_reads

    // ---- MFMA: acc[6 htiles][3 gates], A read once per ks, W streamed ----
    const bf16x8* wp = (const bf16x8*)ws;
    f32x4 acc[6][3];
    #pragma unroll
    for (int ht = 0; ht < 6; ++ht)
        #pragma unroll
        for (int g = 0; g < 3; ++g)
            acc[ht][g] = (f32x4){0.f, 0.f, 0.f, 0.f};

    #pragma unroll
    for (int ks = 0; ks < 6; ++ks) {
        bf16x8 a = *(const bf16x8*)(&aBuf[n * KP + sg16(ks * 8 + 2 * q, n) * 4]);
        #pragma unroll
        for (int ht = 0; ht < 6; ++ht) {
            bf16x8 w0 = wp[((0 * 6 + ks) * 6 + ht) * 64 + lane];
            bf16x8 w1 = wp[((1 * 6 + ks) * 6 + ht) * 64 + lane];
            bf16x8 w2 = wp[((2 * 6 + ks) * 6 + ht) * 64 + lane];
            acc[ht][0] = __builtin_amdgcn_mfma_f32_16x16x32_bf16(a, w0, acc[ht][0], 0, 0, 0);
            acc[ht][1] = __builtin_amdgcn_mfma_f32_16x16x32_bf16(a, w1, acc[ht][1], 0, 0, 0);
            acc[ht][2] = __builtin_amdgcn_mfma_f32_16x16x32_bf16(a, w2, acc[ht][2], 0, 0, 0);
        }
    }

    // ---- epilogue: bias already in acc; one wave owns its whole out rows ----
    // C/D layout: col = lane&15 = n -> h = ht*16+n; row = q*4+e -> t in tile
    float* ob = out + (size_t)b * (T_SZ * H_SZ) + (size_t)(mt * TT) * H_SZ;
    #pragma unroll
    for (int ht = 0; ht < 6; ++ht) {
        const int  h  = ht * 16 + n;
        const bool hv = (h < H_SZ);        // only ht==5, n>=10 invalid
        #pragma unroll
        for (int e = 0; e < 4; ++e) {
            float gi = acc[ht][0][e];
            float gg = acc[ht][1][e];
            float go = acc[ht][2][e];
            float cc = sigmoidf_(gi) * tanhf_(gg);
            float hh = sigmoidf_(go) * tanhf_(cc);
            float v  = sigmoidf_(hh);
            if (hv) ob[(size_t)(q * 4 + e) * H_SZ + h] = v;
        }
    }
}

extern "C" void kernel_launch(void* const* d_in, const int* in_sizes, int n_in,
                              void* d_out, int out_size, void* d_ws, size_t ws_size,
                              hipStream_t stream) {
    const float* x    = (const float*)d_in[0];
    const float* W_ih = (const float*)d_in[1];
    // d_in[2] = W_hh: dead (h0 = c0 = 0 at every timestep)
    const float* b_ih = (const float*)d_in[3];
    const float* b_hh = (const float*)d_in[4];
    float* out = (float*)d_out;

    // ~110 KB workspace: prepacked W fragments with fused-bias row at k=180
    prepack_kernel<<<dim3(18), dim3(384), 0, stream>>>(W_ih, b_ih, b_hh, d_ws);
    lstm_fused_kernel<<<dim3(NMT, B_SZ), dim3(64), 0, stream>>>(x, d_ws, out);
}

// Round 10
// 619.912 us; speedup vs baseline: 1.0851x; 1.0851x over previous
//
#include <hip/hip_runtime.h>

// Encoder_8718783611479: stateless per-step LSTMCell => one GEMM + elementwise.
//   gates = xt @ W_ih^T (+ b_ih + b_hh), only i,g,o gates live (f * c_prev = 0)
//   out = sigmoid(sigmoid(o_g)*tanh(sigmoid(i_g)*tanh(g_g)))
// xt[b,t,k] = x[b*43200 + k*240 + t]  (K=180 strided, M=t contiguous)
//
// v11 = v8 WITHOUT the waves_per_eu(3,3) pin (= v5 + staging-load hoist).
// v10 (single-wave blocks) broke both traffic invariants: FETCH +214MB
// (128B x-lines span TWO 16-t tiles -> fetched twice) and WRITE 2.05x
// (30720 tiny write bursts -> L2 write-merge pressure). v8's pin clamped
// occupancy to 12 waves/CU and cost 190->224. The v5 structure is the only
// one with ideal FETCH+WRITE; its ~24-30 waves/CU occupancy was the real
// win (resident-W was a myth: allocator remats W from the L2 pack at 72-84
// VGPR no matter the budget). This build: v5 structure + all 12 staging
// loads hoisted ahead of W-loads/zero-fill/ds_writes (max MLP in the
// staging burst), allocator free to pick its occupancy.

#define B_SZ 2048
#define T_SZ 240
#define K_SZ 180
#define H_SZ 90
#define KP   192   // K padded to 6*32
#define TB   80    // t per block
#define NP   3     // parts per batch
#define NTT  5     // 16-row t-tiles per block

#define WS_B_OFF 110592   // W frags [3][6][6][64]x16B, then [3][96] f32 biases

typedef __bf16 bf16x8 __attribute__((ext_vector_type(8)));
typedef __bf16 bf16x4 __attribute__((ext_vector_type(4)));
typedef float  f32x4  __attribute__((ext_vector_type(4)));

__device__ __forceinline__ float sigmoidf_(float x) {
    return __builtin_amdgcn_rcpf(1.0f + __expf(-x));
}
__device__ __forceinline__ float tanhf_(float x) {
    return 1.0f - 2.0f * __builtin_amdgcn_rcpf(__expf(2.0f * x) + 1.0f);
}

// Even XOR key per row t; granule = 4 bf16 = 8B. Swizzle within 16-granule
// (128B) groups. Even key preserves b128 granule-pair adjacency (so the
// fragment read is one aligned ds_read_b128). Measured conflicts: negligible.
__device__ __forceinline__ int skey(int t) {
    return (2 * (t + (t >> 4))) & 14;
}
__device__ __forceinline__ int sgran(int g, int t) {
    return (g & ~15) | ((g ^ skey(t)) & 15);
}

// ---------------- prepack: W fragments + fused bias into d_ws ----------------
__global__ __launch_bounds__(384) void prepack_kernel(
    const float* __restrict__ W_ih,
    const float* __restrict__ b_ih,
    const float* __restrict__ b_hh,
    void* __restrict__ ws)
{
    __bf16* wp = (__bf16*)ws;
    float*  bp = (float*)((char*)ws + WS_B_OFF);
    const int gb[3] = {0, 180, 270};   // i, g, o row bases in W_ih (4H=360 rows)

    const int bid = blockIdx.x;
    const int tid = threadIdx.x;
    if (bid < 18) {
        const int g  = bid / 6;
        const int ks = bid % 6;
        const int w  = tid >> 6;
        const int l  = tid & 63;
        const int q  = l >> 4;
        const int n  = l & 15;
        const int h  = w * 16 + n;
        bf16x8 f;
        #pragma unroll
        for (int j = 0; j < 8; ++j) {
            int k = ks * 32 + q * 8 + j;
            float v = (h < H_SZ && k < K_SZ) ? W_ih[(size_t)(gb[g] + h) * K_SZ + k] : 0.0f;
            f[j] = (__bf16)v;
        }
        // fragment order: [g][ks][wave][lane] x 16B -> coalesced load in main
        *(bf16x8*)(wp + (size_t)(((g * 6 + ks) * 6 + w) * 64 + l) * 8) = f;
    } else {
        if (tid < 288) {
            int g = tid / 96, hh = tid % 96;
            bp[g * 96 + hh] = (hh < H_SZ) ? (b_ih[gb[g] + hh] + b_hh[gb[g] + hh]) : 0.0f;
        }
    }
}

// ---------------- main kernel ----------------
__global__ __launch_bounds__(384, 3) void lstm_fused_kernel(
    const float* __restrict__ x,
    const void*  __restrict__ ws,
    float* __restrict__ out)
{
    __shared__ __align__(16) __bf16 aBuf[TB * KP];   // 30.7 KB, swizzled [t][k]

    const int bid  = blockIdx.x;
    const int b    = bid / NP;
    const int part = bid - b * NP;
    const int t0   = part * TB;

    const int tid  = threadIdx.x;
    const int wave = tid >> 6;      // 0..5 -> h-tile
    const int lane = tid & 63;
    const int q    = lane >> 4;     // quad 0..3
    const int n    = lane & 15;
    const int h    = wave * 16 + n; // output column; valid if < 90
    const bool hv  = (h < H_SZ);

    const float* xb = x + (size_t)b * (K_SZ * T_SZ) + t0;

    // staging geometry: unit u -> (k4 = u/20, t4 = u%20); 900 units total
    const int k4a = tid / 20,         t4a = tid - (tid / 20) * 20;
    const int k4b = (tid + 384) / 20, t4b = (tid + 384) - ((tid + 384) / 20) * 20;
    const int k4c = (tid + 768) / 20, t4c = (tid + 768) - ((tid + 768) / 20) * 20;
    const bool u2v = (tid < 132);     // unit tid+768 < 900

    // ---- issue ALL staging loads first (max memory-level parallelism) ----
    f32x4 r0[4], r1[4], r2[4];
    {
        const float* sa = xb + (k4a * 4) * T_SZ + t4a * 4;
        const float* sb = xb + (k4b * 4) * T_SZ + t4b * 4;
        const float* sc = xb + (k4c * 4) * T_SZ + t4c * 4;
        #pragma unroll
        for (int r = 0; r < 4; ++r) r0[r] = *(const f32x4*)(sa + r * T_SZ);
        #pragma unroll
        for (int r = 0; r < 4; ++r) r1[r] = *(const f32x4*)(sb + r * T_SZ);
        if (u2v) {
            #pragma unroll
            for (int r = 0; r < 4; ++r) r2[r] = *(const f32x4*)(sc + r * T_SZ);
        }
    }

    const float* bp = (const float*)((const char*)ws + WS_B_OFF);
    const float bias_i = bp[0 * 96 + h];   // h <= 95, zero-padded
    const float bias_g = bp[1 * 96 + h];
    const float bias_o = bp[2 * 96 + h];
    float* ob = out + (size_t)b * (T_SZ * H_SZ) + (size_t)t0 * H_SZ;

    // zero-fill k-padding granules 45..47 (per-row bijection: no collisions)
    if (tid < TB * 3) {
        int t  = tid / 3;
        int gz = 45 + (tid - (tid / 3) * 3);
        *(unsigned long long*)(aBuf + t * KP + sgran(gz, t) * 4) = 0ull;
    }

    // ---- register 4x4 transpose + packed b64 LDS writes ----
#define WRITEU(R, K4, T4)                                               \
    {                                                                   \
        _Pragma("unroll")                                               \
        for (int j = 0; j < 4; ++j) {                                   \
            int t = (T4) * 4 + j;                                       \
            bf16x4 w;                                                   \
            w[0] = (__bf16)R[0][j]; w[1] = (__bf16)R[1][j];             \
            w[2] = (__bf16)R[2][j]; w[3] = (__bf16)R[3][j];             \
            *(bf16x4*)(aBuf + t * KP + sgran((K4), t) * 4) = w;         \
        }                                                               \
    }
    WRITEU(r0, k4a, t4a);
    WRITEU(r1, k4b, t4b);
    if (u2v) WRITEU(r2, k4c, t4c);
#undef WRITEU

    __syncthreads();   // staging complete

    const bf16x8* wp = (const bf16x8*)ws;

    // ---- tt-outer: per-tile MFMA + immediate compact epilogue ----
    #pragma unroll
    for (int tt = 0; tt < NTT; ++tt) {
        f32x4 acc0 = {0.f, 0.f, 0.f, 0.f};
        f32x4 acc1 = {0.f, 0.f, 0.f, 0.f};
        f32x4 acc2 = {0.f, 0.f, 0.f, 0.f};
        const int t = tt * 16 + n;
        #pragma unroll
        for (int ks = 0; ks < 6; ++ks) {
            // W fragments: coalesced 16B loads from the L2-hot pack (remat
            // per use is the measured-best pattern on this allocator)
            bf16x8 b0 = wp[((0 * 6 + ks) * 6 + wave) * 64 + lane];
            bf16x8 b1 = wp[((1 * 6 + ks) * 6 + wave) * 64 + lane];
            bf16x8 b2 = wp[((2 * 6 + ks) * 6 + wave) * 64 + lane];
            int g = ks * 8 + 2 * q;            // even granule-pair base
            bf16x8 a = *(const bf16x8*)(aBuf + t * KP + sgran(g, t) * 4);
            acc0 = __builtin_amdgcn_mfma_f32_16x16x32_bf16(a, b0, acc0, 0, 0, 0);
            acc1 = __builtin_amdgcn_mfma_f32_16x16x32_bf16(a, b1, acc1, 0, 0, 0);
            acc2 = __builtin_amdgcn_mfma_f32_16x16x32_bf16(a, b2, acc2, 0, 0, 0);
        }
        // C/D layout: col = lane&15 -> h, row = q*4+e -> t within tile
        if (hv) {
            const int tg = tt * 16 + q * 4;
            #pragma unroll
            for (int e = 0; e < 4; ++e) {
                float gi = acc0[e] + bias_i;
                float gg = acc1[e] + bias_g;
                float go = acc2[e] + bias_o;
                float cc = sigmoidf_(gi) * tanhf_(gg);
                float hh = sigmoidf_(go) * tanhf_(cc);
                ob[(size_t)(tg + e) * H_SZ + h] = sigmoidf_(hh);
            }
        }
        // wave re-alignment only (no data dependency): keeps all 6 waves'
        // stores to each out line within one tile window -> single writeback
        if (tt + 1 < NTT) __builtin_amdgcn_s_barrier();
    }
}

extern "C" void kernel_launch(void* const* d_in, const int* in_sizes, int n_in,
                              void* d_out, int out_size, void* d_ws, size_t ws_size,
                              hipStream_t stream) {
    const float* x    = (const float*)d_in[0];
    const float* W_ih = (const float*)d_in[1];
    // d_in[2] = W_hh: dead (h0 = c0 = 0 at every timestep)
    const float* b_ih = (const float*)d_in[3];
    const float* b_hh = (const float*)d_in[4];
    float* out = (float*)d_out;

    // ~112 KB of workspace: prepacked W fragments + fused biases
    prepack_kernel<<<dim3(19), dim3(384), 0, stream>>>(W_ih, b_ih, b_hh, d_ws);
    lstm_fused_kernel<<<dim3(B_SZ * NP), dim3(384), 0, stream>>>(x, d_ws, out);
}

// Round 11
// 553.659 us; speedup vs baseline: 1.2149x; 1.1197x over previous
//
#include <hip/hip_runtime.h>

// Encoder_8718783611479: stateless per-step LSTMCell => one GEMM + elementwise.
//   gates = xt @ W_ih^T (+ b_ih + b_hh), only i,g,o gates live (f * c_prev = 0)
//   out = sigmoid(sigmoid(o_g)*tanh(sigmoid(i_g)*tanh(g_g)))
// xt[b,t,k] = x[b*43200 + k*240 + t]  (K=180 strided, M=t contiguous)
//
// v12 = exact v5 revert (the measured best: ~186us kernel, bench 556).
// Isolated A/B across rounds: v5=186, v5+hoist=252 (v11), v5+hoist+pin=224
// (v8) -> BOTH the staging-load hoist and the waves_per_eu pin are
// regressions. v5's per-unit load->cvt->write staging lets the compiler
// software-pipeline units within its preferred ~72-84 VGPR budget; explicit
// hoisting forces a long vmcnt drain chain instead. All other structural
// deviations (v6 streamed-W, v7 persistent pipeline, v9 per-tile pipeline,
// v10 single-wave blocks) each broke a traffic invariant (FETCH or WRITE) or
// lost occupancy. v5's mechanisms: one-shot swizzled LDS stage (register 4x4
// transpose, packed b64 writes), tt-outer per-tile MFMA + immediate compact
// epilogue, realign s_barrier between tiles (WRITE_SIZE exactly ideal
// 172.8MB), W rematerialized per tile from the prepacked L2-hot pack.

#define B_SZ 2048
#define T_SZ 240
#define K_SZ 180
#define H_SZ 90
#define KP   192   // K padded to 6*32
#define TB   80    // t per block
#define NP   3     // parts per batch
#define NTT  5     // 16-row t-tiles per block

#define WS_B_OFF 110592   // W frags [3][6][6][64]x16B, then [3][96] f32 biases

typedef __bf16 bf16x8 __attribute__((ext_vector_type(8)));
typedef __bf16 bf16x4 __attribute__((ext_vector_type(4)));
typedef float  f32x4  __attribute__((ext_vector_type(4)));

__device__ __forceinline__ float sigmoidf_(float x) {
    return __builtin_amdgcn_rcpf(1.0f + __expf(-x));
}
__device__ __forceinline__ float tanhf_(float x) {
    return 1.0f - 2.0f * __builtin_amdgcn_rcpf(__expf(2.0f * x) + 1.0f);
}

// Even XOR key per row t; granule = 4 bf16 = 8B. Swizzle within 16-granule
// (128B) groups. Even key preserves b128 granule-pair adjacency (so the
// fragment read is one aligned ds_read_b128). Measured conflicts: negligible.
__device__ __forceinline__ int skey(int t) {
    return (2 * (t + (t >> 4))) & 14;
}
__device__ __forceinline__ int sgran(int g, int t) {
    return (g & ~15) | ((g ^ skey(t)) & 15);
}

// ---------------- prepack: W fragments + fused bias into d_ws ----------------
__global__ __launch_bounds__(384) void prepack_kernel(
    const float* __restrict__ W_ih,
    const float* __restrict__ b_ih,
    const float* __restrict__ b_hh,
    void* __restrict__ ws)
{
    __bf16* wp = (__bf16*)ws;
    float*  bp = (float*)((char*)ws + WS_B_OFF);
    const int gb[3] = {0, 180, 270};   // i, g, o row bases in W_ih (4H=360 rows)

    const int bid = blockIdx.x;
    const int tid = threadIdx.x;
    if (bid < 18) {
        const int g  = bid / 6;
        const int ks = bid % 6;
        const int w  = tid >> 6;
        const int l  = tid & 63;
        const int q  = l >> 4;
        const int n  = l & 15;
        const int h  = w * 16 + n;
        bf16x8 f;
        #pragma unroll
        for (int j = 0; j < 8; ++j) {
            int k = ks * 32 + q * 8 + j;
            float v = (h < H_SZ && k < K_SZ) ? W_ih[(size_t)(gb[g] + h) * K_SZ + k] : 0.0f;
            f[j] = (__bf16)v;
        }
        // fragment order: [g][ks][wave][lane] x 16B -> coalesced load in main
        *(bf16x8*)(wp + (size_t)(((g * 6 + ks) * 6 + w) * 64 + l) * 8) = f;
    } else {
        if (tid < 288) {
            int g = tid / 96, hh = tid % 96;
            bp[g * 96 + hh] = (hh < H_SZ) ? (b_ih[gb[g] + hh] + b_hh[gb[g] + hh]) : 0.0f;
        }
    }
}

// ---------------- main kernel ----------------
__global__ __launch_bounds__(384, 3) void lstm_fused_kernel(
    const float* __restrict__ x,
    const void*  __restrict__ ws,
    float* __restrict__ out)
{
    __shared__ __align__(16) __bf16 aBuf[TB * KP];   // 30.7 KB, swizzled [t][k]

    const int bid  = blockIdx.x;
    const int b    = bid / NP;
    const int part = bid - b * NP;
    const int t0   = part * TB;

    const int tid  = threadIdx.x;
    const int wave = tid >> 6;      // 0..5 -> h-tile
    const int lane = tid & 63;
    const int q    = lane >> 4;     // quad 0..3
    const int n    = lane & 15;
    const int h    = wave * 16 + n; // output column; valid if < 90
    const bool hv  = (h < H_SZ);

    const float* xb = x + (size_t)b * (K_SZ * T_SZ) + t0;

    // zero-fill k-padding granules 45..47 of each row (swizzle is a per-row
    // bijection on slots, so zero slots never collide with data slots)
    if (tid < TB * 3) {
        int t  = tid / 3;
        int gz = 45 + (tid - (tid / 3) * 3);
        *(unsigned long long*)(aBuf + t * KP + sgran(gz, t) * 4) = 0ull;
    }

    // ---- one-shot staging: 900 4x4 blocks, register transpose, b64 writes ----
    #pragma unroll
    for (int p = 0; p < 3; ++p) {
        int u = tid + p * 384;
        if (p < 2 || u < 900) {                  // 45 k-granules x 20 t4
            int k4 = u / 20;
            int t4 = u - k4 * 20;
            const float* src = xb + (k4 * 4) * T_SZ + t4 * 4;
            f32x4 r0 = *(const f32x4*)(src);
            f32x4 r1 = *(const f32x4*)(src + T_SZ);
            f32x4 r2 = *(const f32x4*)(src + 2 * T_SZ);
            f32x4 r3 = *(const f32x4*)(src + 3 * T_SZ);
            #pragma unroll
            for (int j = 0; j < 4; ++j) {
                int t = t4 * 4 + j;
                bf16x4 w;
                w[0] = (__bf16)r0[j]; w[1] = (__bf16)r1[j];
                w[2] = (__bf16)r2[j]; w[3] = (__bf16)r3[j];
                *(bf16x4*)(aBuf + t * KP + sgran(k4, t) * 4) = w;
            }
        }
    }

    // ---- W fragments: resident for the whole kernel (72 VGPR) ----
    const bf16x8* wp = (const bf16x8*)ws;
    bf16x8 bfrag[3][6];
    #pragma unroll
    for (int g = 0; g < 3; ++g)
        #pragma unroll
        for (int ks = 0; ks < 6; ++ks)
            bfrag[g][ks] = wp[((g * 6 + ks) * 6 + wave) * 64 + lane];

    const float* bp = (const float*)((const char*)ws + WS_B_OFF);
    const float bias_i = bp[0 * 96 + h];   // h <= 95, zero-padded
    const float bias_g = bp[1 * 96 + h];
    const float bias_o = bp[2 * 96 + h];
    float* ob = out + (size_t)b * (T_SZ * H_SZ) + (size_t)t0 * H_SZ;

    __syncthreads();   // staging complete

    // ---- tt-outer: per-tile MFMA + immediate compact epilogue ----
    #pragma unroll
    for (int tt = 0; tt < NTT; ++tt) {
        f32x4 acc0 = {0.f, 0.f, 0.f, 0.f};
        f32x4 acc1 = {0.f, 0.f, 0.f, 0.f};
        f32x4 acc2 = {0.f, 0.f, 0.f, 0.f};
        const int t = tt * 16 + n;
        #pragma unroll
        for (int ks = 0; ks < 6; ++ks) {
            int g = ks * 8 + 2 * q;            // even granule-pair base
            bf16x8 a = *(const bf16x8*)(aBuf + t * KP + sgran(g, t) * 4);
            acc0 = __builtin_amdgcn_mfma_f32_16x16x32_bf16(a, bfrag[0][ks], acc0, 0, 0, 0);
            acc1 = __builtin_amdgcn_mfma_f32_16x16x32_bf16(a, bfrag[1][ks], acc1, 0, 0, 0);
            acc2 = __builtin_amdgcn_mfma_f32_16x16x32_bf16(a, bfrag[2][ks], acc2, 0, 0, 0);
        }
        // C/D layout: col = lane&15 -> h, row = q*4+e -> t within tile
        if (hv) {
            const int tg = tt * 16 + q * 4;
            #pragma unroll
            for (int e = 0; e < 4; ++e) {
                float gi = acc0[e] + bias_i;
                float gg = acc1[e] + bias_g;
                float go = acc2[e] + bias_o;
                float cc = sigmoidf_(gi) * tanhf_(gg);
                float hh = sigmoidf_(go) * tanhf_(cc);
                ob[(size_t)(tg + e) * H_SZ + h] = sigmoidf_(hh);
            }
        }
        // wave re-alignment only (no data dependency): keeps all 6 waves'
        // stores to each out line within one tile window -> single writeback
        if (tt + 1 < NTT) __builtin_amdgcn_s_barrier();
    }
}

extern "C" void kernel_launch(void* const* d_in, const int* in_sizes, int n_in,
                              void* d_out, int out_size, void* d_ws, size_t ws_size,
                              hipStream_t stream) {
    const float* x    = (const float*)d_in[0];
    const float* W_ih = (const float*)d_in[1];
    // d_in[2] = W_hh: dead (h0 = c0 = 0 at every timestep)
    const float* b_ih = (const float*)d_in[3];
    const float* b_hh = (const float*)d_in[4];
    float* out = (float*)d_out;

    // ~112 KB of workspace: prepacked W fragments + fused biases
    prepack_kernel<<<dim3(19), dim3(384), 0, stream>>>(W_ih, b_ih, b_hh, d_ws);
    lstm_fused_kernel<<<dim3(B_SZ * NP), dim3(384), 0, stream>>>(x, d_ws, out);
}